// Round 2
// baseline (686.977 us; speedup 1.0000x reference)
//
#include <hip/hip_runtime.h>
#include <cstdint>

#define B_SZ 4096
#define T_SZ 1000
#define I_SZ 3
#define H_SZ 10
#define GPW  6          // batch groups per wave (10 lanes each; lanes 60-63 dummy group 6)
#define GRP_STRIDE 40   // words per group slot in LDS (160B, 16B-aligned)

__device__ __forceinline__ float fsig(float s) {
    // sigmoid(s) = 1/(1+e^-s); inf-safe: s<<0 -> e=inf -> rcp=0; s>>0 -> e=0 -> 1
    float e = __expf(-s);
    return __builtin_amdgcn_rcpf(1.0f + e);
}
__device__ __forceinline__ float ftanh(float y) {
    // tanh(y) = 1 - 2/(e^{2y}+1); inf-safe at both ends (no inf*0)
    float e2 = __expf(y + y);
    return 1.0f - 2.0f * __builtin_amdgcn_rcpf(e2 + 1.0f);
}

// acc += dot(W[g_][0:10], {v0.xyzw, v1.xyzw, v2.xy})
#define DOT10(W, g_, v0, v1, v2, acc) do { \
    acc = fmaf(W[g_][0], (v0).x, acc); \
    acc = fmaf(W[g_][1], (v0).y, acc); \
    acc = fmaf(W[g_][2], (v0).z, acc); \
    acc = fmaf(W[g_][3], (v0).w, acc); \
    acc = fmaf(W[g_][4], (v1).x, acc); \
    acc = fmaf(W[g_][5], (v1).y, acc); \
    acc = fmaf(W[g_][6], (v1).z, acc); \
    acc = fmaf(W[g_][7], (v1).w, acc); \
    acc = fmaf(W[g_][8], (v2).x, acc); \
    acc = fmaf(W[g_][9], (v2).y, acc); \
} while (0)

__global__ __launch_bounds__(64, 1) void gru3_fused(
    const float* __restrict__ x,
    const float* __restrict__ Wih0, const float* __restrict__ Whh0,
    const float* __restrict__ bih0, const float* __restrict__ bhh0,
    const float* __restrict__ Wih1, const float* __restrict__ Whh1,
    const float* __restrict__ bih1, const float* __restrict__ bhh1,
    const float* __restrict__ Wih2, const float* __restrict__ Whh2,
    const float* __restrict__ bih2, const float* __restrict__ bhh2,
    const float* __restrict__ Wout, const float* __restrict__ bout,
    float* __restrict__ out)
{
    __shared__ __align__(16) float lds[7 * GRP_STRIDE];

    const int lane  = threadIdx.x;     // block = 1 wave of 64
    const int j     = lane % H_SZ;     // hidden unit 0..9
    const int g     = lane / H_SZ;     // group 0..6 (6 = dummy, never stores)
    const int b_raw = blockIdx.x * GPW + g;
    const int b     = b_raw < B_SZ ? b_raw : (B_SZ - 1);

    // ---- weights for this lane's unit j, all in registers ----
    float wi0[3][I_SZ], wh0[3][H_SZ];
    float wi1[3][H_SZ], wh1[3][H_SZ];
    float wi2[3][H_SZ], wh2[3][H_SZ];
#pragma unroll
    for (int gg = 0; gg < 3; ++gg) {
        const int row = gg * H_SZ + j;
#pragma unroll
        for (int i = 0; i < I_SZ; ++i) wi0[gg][i] = Wih0[row * I_SZ + i];
#pragma unroll
        for (int k = 0; k < H_SZ; ++k) wh0[gg][k] = Whh0[row * H_SZ + k];
#pragma unroll
        for (int k = 0; k < H_SZ; ++k) wi1[gg][k] = Wih1[row * H_SZ + k];
#pragma unroll
        for (int k = 0; k < H_SZ; ++k) wh1[gg][k] = Whh1[row * H_SZ + k];
#pragma unroll
        for (int k = 0; k < H_SZ; ++k) wi2[gg][k] = Wih2[row * H_SZ + k];
#pragma unroll
        for (int k = 0; k < H_SZ; ++k) wh2[gg][k] = Whh2[row * H_SZ + k];
    }
    // biases: r,z get combined (bih+bhh); n keeps them separate (bhh_n is scaled by r)
    const float br0 = bih0[j] + bhh0[j], bz0 = bih0[H_SZ + j] + bhh0[H_SZ + j];
    const float bni0 = bih0[2 * H_SZ + j], bnh0 = bhh0[2 * H_SZ + j];
    const float br1 = bih1[j] + bhh1[j], bz1 = bih1[H_SZ + j] + bhh1[H_SZ + j];
    const float bni1 = bih1[2 * H_SZ + j], bnh1 = bhh1[2 * H_SZ + j];
    const float br2 = bih2[j] + bhh2[j], bz2 = bih2[H_SZ + j] + bhh2[H_SZ + j];
    const float bni2 = bih2[2 * H_SZ + j], bnh2 = bhh2[2 * H_SZ + j];

    const int gb = g * GRP_STRIDE;
    // init h = 0 (words 10,11 of each 12-word layer slot are read as float4 tails
    // but never used in the dot products)
    lds[gb + j]      = 0.0f;
    lds[gb + 12 + j] = 0.0f;
    lds[gb + 24 + j] = 0.0f;
    float h0 = 0.0f, h1 = 0.0f, h2 = 0.0f;   // this lane's own elements

    const float* xp = x + (size_t)b * (T_SZ * I_SZ);

    // x software-prefetch: registers hold x[t] for the CURRENT iteration while
    // the loads for t+1 are in flight underneath the ~500-cycle layer bodies
    // (1 wave/SIMD -> no TLP; latency must be hidden by ILP).
    float cx0 = xp[0], cx1 = xp[1], cx2 = xp[2];

    // Layer-pipelined: iter it computes L0@step it, L1@step it-1, L2@step it-2.
    // All LDS reads at the top of the iteration are of values written in PREVIOUS
    // iterations -> the three layer bodies are mutually independent (ILP).
#pragma unroll 1
    for (int it = 0; it < T_SZ + 2; ++it) {
        const float4* pa = reinterpret_cast<const float4*>(&lds[gb]);
        const float4 A0 = pa[0], A1 = pa[1], A2 = pa[2];          // h0(it-1)
        const float4* pb = reinterpret_cast<const float4*>(&lds[gb + 12]);
        const float4 B0 = pb[0], B1 = pb[1], B2 = pb[2];          // h1(it-2)
        const float4* pc = reinterpret_cast<const float4*>(&lds[gb + 24]);
        const float4 C0 = pc[0], C1 = pc[1], C2 = pc[2];          // h2(it-3)

        const float x0 = cx0, x1 = cx1, x2 = cx2;
        const int tn = (it + 1 < T_SZ) ? it + 1 : (T_SZ - 1);     // clamp: no OOB
        cx0 = xp[tn * 3 + 0];
        cx1 = xp[tn * 3 + 1];
        cx2 = xp[tn * 3 + 2];

        if (it < T_SZ) {                       // ---- layer 0, step it ----
            float ar = br0, az = bz0, axn = bni0, ahn = bnh0;
            ar  = fmaf(wi0[0][0], x0, ar);  ar  = fmaf(wi0[0][1], x1, ar);  ar  = fmaf(wi0[0][2], x2, ar);
            az  = fmaf(wi0[1][0], x0, az);  az  = fmaf(wi0[1][1], x1, az);  az  = fmaf(wi0[1][2], x2, az);
            axn = fmaf(wi0[2][0], x0, axn); axn = fmaf(wi0[2][1], x1, axn); axn = fmaf(wi0[2][2], x2, axn);
            DOT10(wh0, 0, A0, A1, A2, ar);
            DOT10(wh0, 1, A0, A1, A2, az);
            DOT10(wh0, 2, A0, A1, A2, ahn);
            const float r = fsig(ar), z = fsig(az);
            const float n = ftanh(fmaf(r, ahn, axn));
            h0 = fmaf(z, h0 - n, n);           // (1-z)n + z h
            lds[gb + j] = h0;
        }
        if (it >= 1 && it <= T_SZ) {           // ---- layer 1, step it-1, input A ----
            float ar = br1, az = bz1, axn = bni1, ahn = bnh1;
            DOT10(wi1, 0, A0, A1, A2, ar);
            DOT10(wi1, 1, A0, A1, A2, az);
            DOT10(wi1, 2, A0, A1, A2, axn);
            DOT10(wh1, 0, B0, B1, B2, ar);
            DOT10(wh1, 1, B0, B1, B2, az);
            DOT10(wh1, 2, B0, B1, B2, ahn);
            const float r = fsig(ar), z = fsig(az);
            const float n = ftanh(fmaf(r, ahn, axn));
            h1 = fmaf(z, h1 - n, n);
            lds[gb + 12 + j] = h1;
        }
        if (it >= 2) {                         // ---- layer 2, step it-2, input B ----
            float ar = br2, az = bz2, axn = bni2, ahn = bnh2;
            DOT10(wi2, 0, B0, B1, B2, ar);
            DOT10(wi2, 1, B0, B1, B2, az);
            DOT10(wi2, 2, B0, B1, B2, axn);
            DOT10(wh2, 0, C0, C1, C2, ar);
            DOT10(wh2, 1, C0, C1, C2, az);
            DOT10(wh2, 2, C0, C1, C2, ahn);
            const float r = fsig(ar), z = fsig(az);
            const float n = ftanh(fmaf(r, ahn, axn));
            h2 = fmaf(z, h2 - n, n);
            lds[gb + 24 + j] = h2;
        }
    }

    // ---- output projection: out[b] = h2(T-1) . Wout + bout ----
    if (j == 0 && g < GPW && b_raw < B_SZ) {
        const float* hv = &lds[gb + 24];
        float acc = bout[0];
#pragma unroll
        for (int k = 0; k < H_SZ; ++k) acc = fmaf(hv[k], Wout[k], acc);
        out[b_raw] = acc;
    }
}

extern "C" void kernel_launch(void* const* d_in, const int* in_sizes, int n_in,
                              void* d_out, int out_size, void* d_ws, size_t ws_size,
                              hipStream_t stream) {
    const float* x    = (const float*)d_in[0];
    const float* Wih0 = (const float*)d_in[1];
    const float* Whh0 = (const float*)d_in[2];
    const float* bih0 = (const float*)d_in[3];
    const float* bhh0 = (const float*)d_in[4];
    const float* Wih1 = (const float*)d_in[5];
    const float* Whh1 = (const float*)d_in[6];
    const float* bih1 = (const float*)d_in[7];
    const float* bhh1 = (const float*)d_in[8];
    const float* Wih2 = (const float*)d_in[9];
    const float* Whh2 = (const float*)d_in[10];
    const float* bih2 = (const float*)d_in[11];
    const float* bhh2 = (const float*)d_in[12];
    const float* Wout = (const float*)d_in[13];
    const float* bout = (const float*)d_in[14];
    float* out = (float*)d_out;

    const int grid = (B_SZ + GPW - 1) / GPW;   // 683 blocks x 1 wave
    gru3_fused<<<grid, 64, 0, stream>>>(x, Wih0, Whh0, bih0, bhh0,
                                        Wih1, Whh1, bih1, bhh1,
                                        Wih2, Whh2, bih2, bhh2,
                                        Wout, bout, out);
}